// Round 8
// baseline (566.090 us; speedup 1.0000x reference)
//
#include <hip/hip_runtime.h>
#include <hip/hip_bf16.h>
#include <math.h>

// Problem constants (fixed by the reference)
#define NN 50000
#define NE 800000
#define NPAD 50048   // 782 * 64 — tail-free GEMM tiles
#define NB_SCAN 196  // ceil(NN/256)

typedef unsigned short u16;
typedef unsigned int u32;
typedef __attribute__((ext_vector_type(8))) short short8;   // 8 bf16 (MFMA A/B frag)
typedef __attribute__((ext_vector_type(4))) float float4v;  // MFMA C/D frag

__device__ __forceinline__ float us2f(u16 u) { return __uint_as_float(((unsigned)u) << 16); }
__device__ __forceinline__ float blo(u32 u) { return __uint_as_float(u << 16); }
__device__ __forceinline__ float bhi(u32 u) { return __uint_as_float(u & 0xffff0000u); }
__device__ __forceinline__ u16 f2us(float f) {   // fp32 -> bf16 RNE
    unsigned x = __float_as_uint(f);
    return (u16)((x + 0x7FFFu + ((x >> 16) & 1u)) >> 16);
}
// tanh-gelu via sigmoid identity: 0.5*(1+tanh(u)) = sigmoid(2u)
__device__ __forceinline__ float gelu_f(float x) {
    float p = x * x;
    float t = x * fmaf(p, 0.0713548162726f, 1.5957691216057308f);  // 2u
    float e = __expf(-t);
    return x * __builtin_amdgcn_rcpf(1.0f + e);
}
// intra-wave LDS ordering fence (no cross-wave barrier needed: LDS regions are wave-private)
__device__ __forceinline__ void lds_fence() {
    asm volatile("s_waitcnt lgkmcnt(0)" ::: "memory");
}

__device__ __forceinline__ float4v mfma4(const u16* __restrict__ Wbase, int wrow, int m, int kb,
                                         short8 a0, short8 a1, short8 a2, short8 a3) {
    const short8* wr = (const short8*)(Wbase + (size_t)(wrow + m) * 128);
    short8 b0 = wr[kb], b1 = wr[kb + 4], b2 = wr[kb + 8], b3 = wr[kb + 12];
    float4v acc = {0.f, 0.f, 0.f, 0.f};
    acc = __builtin_amdgcn_mfma_f32_16x16x32_bf16(a0, b0, acc, 0, 0, 0);
    acc = __builtin_amdgcn_mfma_f32_16x16x32_bf16(a1, b1, acc, 0, 0, 0);
    acc = __builtin_amdgcn_mfma_f32_16x16x32_bf16(a2, b2, acc, 0, 0, 0);
    acc = __builtin_amdgcn_mfma_f32_16x16x32_bf16(a3, b3, acc, 0, 0, 0);
    return acc;
}

// ---------------- CSR build ----------------

__global__ void k_hist(const int* __restrict__ dstv, int* __restrict__ deg) {
    int e = blockIdx.x * blockDim.x + threadIdx.x;
    if (e < NE) atomicAdd(&deg[dstv[e]], 1);
}

__global__ __launch_bounds__(256) void k_scan1(const int* __restrict__ deg,
                                               int* __restrict__ rowstart,
                                               int* __restrict__ bsum) {
    __shared__ int wtot[4];
    int i = blockIdx.x * 256 + threadIdx.x;
    int lane = threadIdx.x & 63, w = threadIdx.x >> 6;
    int v = (i < NN) ? deg[i] : 0;
    int incl = v;
#pragma unroll
    for (int d = 1; d < 64; d <<= 1) {
        int tv = __shfl_up(incl, d);
        if (lane >= d) incl += tv;
    }
    if (lane == 63) wtot[w] = incl;
    __syncthreads();
    if (threadIdx.x == 0) {
        int s = 0;
#pragma unroll
        for (int j = 0; j < 4; ++j) { int t = wtot[j]; wtot[j] = s; s += t; }
        bsum[blockIdx.x] = s;
    }
    __syncthreads();
    if (i < NN) rowstart[i] = incl - v + wtot[w];
}

__global__ __launch_bounds__(256) void k_scan2(int* __restrict__ bsum) {
    __shared__ int wtot[4];
    int t = threadIdx.x;
    int lane = t & 63, w = t >> 6;
    int v = (t < NB_SCAN) ? bsum[t] : 0;
    int incl = v;
#pragma unroll
    for (int d = 1; d < 64; d <<= 1) {
        int tv = __shfl_up(incl, d);
        if (lane >= d) incl += tv;
    }
    if (lane == 63) wtot[w] = incl;
    __syncthreads();
    if (t == 0) {
        int s = 0;
#pragma unroll
        for (int j = 0; j < 4; ++j) { int tt = wtot[j]; wtot[j] = s; s += tt; }
    }
    __syncthreads();
    if (t < NB_SCAN) bsum[t] = incl - v + wtot[w];
}

__global__ void k_scan3(const int* __restrict__ bsum, int* __restrict__ rowstart,
                        int* __restrict__ cursor) {
    int i = blockIdx.x * 256 + threadIdx.x;
    if (i < NN) {
        int v = rowstart[i] + bsum[blockIdx.x];
        rowstart[i] = v;
        cursor[i] = v;
    }
    if (i == 0) rowstart[NN] = NE;
}

__global__ void k_scatter(const int* __restrict__ srcv, const int* __restrict__ dstv,
                          const float* __restrict__ eattr, int* __restrict__ cursor,
                          int4* __restrict__ rec) {
    int e = blockIdx.x * blockDim.x + threadIdx.x;
    if (e >= NE) return;
    int dst = dstv[e];
    int pos = atomicAdd(&cursor[dst], 1);
    int4 r;
    r.x = srcv[e];
    r.y = __float_as_int(eattr[e * 3 + 0]);
    r.z = __float_as_int(eattr[e * 3 + 1]);
    r.w = __float_as_int(eattr[e * 3 + 2]);
    rec[pos] = r;
}

// ---------------- weight fp32->bf16 ----------------

struct CvtEnt { const float* s; u16* d; int n; };
struct CvtTab { CvtEnt e[14]; };
__global__ void k_cvt_w(CvtTab tab) {
    CvtEnt E = tab.e[blockIdx.x >> 3];
    int chunk = blockIdx.x & 7;
    int per = E.n >> 3;
    int lo = chunk * per, hi = lo + per;
    for (int i = lo + threadIdx.x; i < hi; i += blockDim.x) E.d[i] = f2us(E.s[i]);
}

// =============== barrier-free, wave-private GEMM chain kernels ===============
// All staging is intra-wave: MFMA C/D rows (kb*4+r) and A-frag rows (m) belong
// to the SAME wave. Each wave owns a private 16x136 LDS tile -> no __syncthreads,
// no vmcnt drains; global stores are fire-and-forget.

// stage one 16-col C/D tile (plain layout) into wave buffer
__device__ __forceinline__ void stage_plain(u16* buf, int kb, int m, int tt, float4v acc) {
#pragma unroll
    for (int r = 0; r < 4; ++r) buf[(kb * 4 + r) * 136 + tt * 16 + m] = f2us(acc[r]);
}
// store wave buffer 16 rows x 128 cols -> dst rows (stride 512), col offset coff
__device__ __forceinline__ void store128(const u16* buf, u16* dst, int r0w, int coff, int l) {
#pragma unroll
    for (int it = 0; it < 4; ++it) {
        int j = it * 64 + l;
        int row = j >> 4, col = (j & 15) * 8;
        *(uint4*)(dst + (size_t)(r0w + row) * 512 + coff + col) = *(const uint4*)&buf[row * 136 + col];
    }
}
// read A-frags (rows m, 128 cols) from wave buffer
__device__ __forceinline__ void read_frags(const u16* buf, int m, int kb,
                                           short8& f0, short8& f1, short8& f2, short8& f3) {
    const u16* p = buf + m * 136 + kb * 8;
    f0 = *(const short8*)(p);
    f1 = *(const short8*)(p + 32);
    f2 = *(const short8*)(p + 64);
    f3 = *(const short8*)(p + 96);
}

// ---------------- layer-1 QKVS GEMM (A = fp32 x) ----------------
// QKVS row (stride 512): [q 0..127 | kv interleaved 128..383 | s 384..511]
// kv[4p+0..3] = {k[2p],k[2p+1],v[2p],v[2p+1]}.

__global__ __launch_bounds__(256) void k_qkvs1(const float* __restrict__ Ain,
                                               const u16* __restrict__ W,
                                               u16* __restrict__ QKVS) {
    __shared__ u16 tile[4][16 * 136];
    int tid = threadIdx.x;
    int l = tid & 63, w = tid >> 6, m = l & 15, kb = l >> 4;
    int r0w = blockIdx.x * 64 + w * 16;
    u16* my = tile[w];

    short8 a0, a1, a2, a3;
    {
        const float* ap = Ain + (size_t)(r0w + m) * 128;
        bool ok = (r0w + m) < NN;
        short8* dsts[4] = {&a0, &a1, &a2, &a3};
#pragma unroll
        for (int i = 0; i < 4; ++i) {
            short8 r;
            if (ok) {
                const float* p = ap + (kb + i * 4) * 8;
                float4 f0 = *(const float4*)p;
                float4 f1 = *(const float4*)(p + 4);
                r[0]=(short)f2us(f0.x); r[1]=(short)f2us(f0.y); r[2]=(short)f2us(f0.z); r[3]=(short)f2us(f0.w);
                r[4]=(short)f2us(f1.x); r[5]=(short)f2us(f1.y); r[6]=(short)f2us(f1.z); r[7]=(short)f2us(f1.w);
            } else {
#pragma unroll
                for (int j = 0; j < 8; ++j) r[j] = 0;
            }
            *dsts[i] = r;
        }
    }

    // ---- q (W rows 0..127) ----
#pragma unroll
    for (int tt = 0; tt < 8; ++tt) stage_plain(my, kb, m, tt, mfma4(W, tt * 16, m, kb, a0, a1, a2, a3));
    lds_fence();
    store128(my, QKVS, r0w, 0, l);
    lds_fence();
    // ---- kv-lo: k tiles 0..3 (W 128..191) + v tiles 0..3 (W 256..319) ----
#pragma unroll
    for (int tt = 0; tt < 4; ++tt) {
        float4v acc = mfma4(W, 128 + tt * 16, m, kb, a0, a1, a2, a3);
        int c = tt * 32 + 4 * (m >> 1) + (m & 1);
#pragma unroll
        for (int r = 0; r < 4; ++r) my[(kb * 4 + r) * 136 + c] = f2us(acc[r]);
    }
#pragma unroll
    for (int tt = 0; tt < 4; ++tt) {
        float4v acc = mfma4(W, 256 + tt * 16, m, kb, a0, a1, a2, a3);
        int c = tt * 32 + 4 * (m >> 1) + (m & 1) + 2;
#pragma unroll
        for (int r = 0; r < 4; ++r) my[(kb * 4 + r) * 136 + c] = f2us(acc[r]);
    }
    lds_fence();
    store128(my, QKVS, r0w, 128, l);
    lds_fence();
    // ---- kv-hi: k tiles 4..7 (W 192..255) + v tiles 4..7 (W 320..383) ----
#pragma unroll
    for (int tt = 0; tt < 4; ++tt) {
        float4v acc = mfma4(W, 192 + tt * 16, m, kb, a0, a1, a2, a3);
        int c = tt * 32 + 4 * (m >> 1) + (m & 1);
#pragma unroll
        for (int r = 0; r < 4; ++r) my[(kb * 4 + r) * 136 + c] = f2us(acc[r]);
    }
#pragma unroll
    for (int tt = 0; tt < 4; ++tt) {
        float4v acc = mfma4(W, 320 + tt * 16, m, kb, a0, a1, a2, a3);
        int c = tt * 32 + 4 * (m >> 1) + (m & 1) + 2;
#pragma unroll
        for (int r = 0; r < 4; ++r) my[(kb * 4 + r) * 136 + c] = f2us(acc[r]);
    }
    lds_fence();
    store128(my, QKVS, r0w, 256, l);
    lds_fence();
    // ---- s (W rows 384..511) ----
#pragma unroll
    for (int tt = 0; tt < 8; ++tt) stage_plain(my, kb, m, tt, mfma4(W, 384 + tt * 16, m, kb, a0, a1, a2, a3));
    lds_fence();
    store128(my, QKVS, r0w, 384, l);
}

// ---------------- fused MLP + next-layer QKVS (barrier-free) ----------------

__global__ __launch_bounds__(256) void k_mlp_qkvs(const u16* __restrict__ Ain,
                                                  const u16* __restrict__ Wm,
                                                  const float* __restrict__ bias1,
                                                  const float* __restrict__ bias2,
                                                  const u16* __restrict__ Wq,
                                                  u16* __restrict__ QKVS) {
    __shared__ u16 shb[4][16 * 136];
    __shared__ u16 t1b[4][16 * 136];
    int tid = threadIdx.x;
    int l = tid & 63, w = tid >> 6, m = l & 15, kb = l >> 4;
    int r0w = blockIdx.x * 64 + w * 16;
    u16* sh = shb[w];
    u16* t1 = t1b[w];

    const short8* arow = (const short8*)(Ain + (size_t)(r0w + m) * 128);
    short8 a0 = arow[kb], a1 = arow[kb + 4], a2 = arow[kb + 8], a3 = arow[kb + 12];
    {   // stage A (residual source), linear rows
        u16* p = sh + m * 136 + kb * 8;
        *(short8*)(p) = a0;
        *(short8*)(p + 32) = a1;
        *(short8*)(p + 64) = a2;
        *(short8*)(p + 96) = a3;
    }
    // GEMM1 -> t1 (gelu)
#pragma unroll
    for (int tt = 0; tt < 8; ++tt) {
        float4v acc = mfma4(Wm, tt * 16, m, kb, a0, a1, a2, a3);
        float bv = bias1[tt * 16 + m];
#pragma unroll
        for (int r = 0; r < 4; ++r)
            t1[(kb * 4 + r) * 136 + tt * 16 + m] = f2us(gelu_f(acc[r] + bv));
    }
    lds_fence();
    short8 c0, c1, c2, c3;
    read_frags(t1, m, kb, c0, c1, c2, c3);
    // GEMM2 + residual -> sh becomes H2 (owner-lane RMW)
#pragma unroll
    for (int tt = 0; tt < 8; ++tt) {
        float4v acc = mfma4(Wm + 16384, tt * 16, m, kb, c0, c1, c2, c3);
        float bv = bias2[tt * 16 + m];
#pragma unroll
        for (int r = 0; r < 4; ++r) {
            int idx = (kb * 4 + r) * 136 + tt * 16 + m;
            sh[idx] = f2us(gelu_f(acc[r] + bv) + us2f(sh[idx]));
        }
    }
    lds_fence();
    short8 h0, h1, h2, h3;
    read_frags(sh, m, kb, h0, h1, h2, h3);

    // ---- q ----
#pragma unroll
    for (int tt = 0; tt < 8; ++tt) stage_plain(t1, kb, m, tt, mfma4(Wq, tt * 16, m, kb, h0, h1, h2, h3));
    lds_fence();
    store128(t1, QKVS, r0w, 0, l);
    lds_fence();
    // ---- kv-lo ----
#pragma unroll
    for (int tt = 0; tt < 4; ++tt) {
        float4v acc = mfma4(Wq, 128 + tt * 16, m, kb, h0, h1, h2, h3);
        int c = tt * 32 + 4 * (m >> 1) + (m & 1);
#pragma unroll
        for (int r = 0; r < 4; ++r) t1[(kb * 4 + r) * 136 + c] = f2us(acc[r]);
    }
#pragma unroll
    for (int tt = 0; tt < 4; ++tt) {
        float4v acc = mfma4(Wq, 256 + tt * 16, m, kb, h0, h1, h2, h3);
        int c = tt * 32 + 4 * (m >> 1) + (m & 1) + 2;
#pragma unroll
        for (int r = 0; r < 4; ++r) t1[(kb * 4 + r) * 136 + c] = f2us(acc[r]);
    }
    lds_fence();
    store128(t1, QKVS, r0w, 128, l);
    lds_fence();
    // ---- kv-hi ----
#pragma unroll
    for (int tt = 0; tt < 4; ++tt) {
        float4v acc = mfma4(Wq, 192 + tt * 16, m, kb, h0, h1, h2, h3);
        int c = tt * 32 + 4 * (m >> 1) + (m & 1);
#pragma unroll
        for (int r = 0; r < 4; ++r) t1[(kb * 4 + r) * 136 + c] = f2us(acc[r]);
    }
#pragma unroll
    for (int tt = 0; tt < 4; ++tt) {
        float4v acc = mfma4(Wq, 320 + tt * 16, m, kb, h0, h1, h2, h3);
        int c = tt * 32 + 4 * (m >> 1) + (m & 1) + 2;
#pragma unroll
        for (int r = 0; r < 4; ++r) t1[(kb * 4 + r) * 136 + c] = f2us(acc[r]);
    }
    lds_fence();
    store128(t1, QKVS, r0w, 256, l);
    lds_fence();
    // ---- s ----
#pragma unroll
    for (int tt = 0; tt < 8; ++tt) stage_plain(t1, kb, m, tt, mfma4(Wq, 384 + tt * 16, m, kb, h0, h1, h2, h3));
    lds_fence();
    store128(t1, QKVS, r0w, 384, l);
}

// ---------------- fused MLP + final MLP (barrier-free) ----------------

__global__ __launch_bounds__(256) void k_mlp_final(const u16* __restrict__ Ain,
                                                   const u16* __restrict__ Wm,
                                                   const float* __restrict__ bias1,
                                                   const float* __restrict__ bias2,
                                                   const u16* __restrict__ Wf,
                                                   const float* __restrict__ bf1,
                                                   const float* __restrict__ bf2,
                                                   float* __restrict__ outp) {
    __shared__ u16 shb[4][16 * 136];
    __shared__ u16 t1b[4][16 * 136];
    int tid = threadIdx.x;
    int l = tid & 63, w = tid >> 6, m = l & 15, kb = l >> 4;
    int r0w = blockIdx.x * 64 + w * 16;
    u16* sh = shb[w];
    u16* t1 = t1b[w];

    const short8* arow = (const short8*)(Ain + (size_t)(r0w + m) * 128);
    short8 a0 = arow[kb], a1 = arow[kb + 4], a2 = arow[kb + 8], a3 = arow[kb + 12];
    {
        u16* p = sh + m * 136 + kb * 8;
        *(short8*)(p) = a0;
        *(short8*)(p + 32) = a1;
        *(short8*)(p + 64) = a2;
        *(short8*)(p + 96) = a3;
    }
#pragma unroll
    for (int tt = 0; tt < 8; ++tt) {
        float4v acc = mfma4(Wm, tt * 16, m, kb, a0, a1, a2, a3);
        float bv = bias1[tt * 16 + m];
#pragma unroll
        for (int r = 0; r < 4; ++r)
            t1[(kb * 4 + r) * 136 + tt * 16 + m] = f2us(gelu_f(acc[r] + bv));
    }
    lds_fence();
    short8 c0, c1, c2, c3;
    read_frags(t1, m, kb, c0, c1, c2, c3);
#pragma unroll
    for (int tt = 0; tt < 8; ++tt) {
        float4v acc = mfma4(Wm + 16384, tt * 16, m, kb, c0, c1, c2, c3);
        float bv = bias2[tt * 16 + m];
#pragma unroll
        for (int r = 0; r < 4; ++r) {
            int idx = (kb * 4 + r) * 136 + tt * 16 + m;
            sh[idx] = f2us(gelu_f(acc[r] + bv) + us2f(sh[idx]));
        }
    }
    lds_fence();
    short8 h0, h1, h2, h3;
    read_frags(sh, m, kb, h0, h1, h2, h3);
    // G3 = gelu(H4@Wf1+bf1) -> t1 (t1 c-frags already consumed)
#pragma unroll
    for (int tt = 0; tt < 8; ++tt) {
        float4v acc = mfma4(Wf, tt * 16, m, kb, h0, h1, h2, h3);
        float bv = bf1[tt * 16 + m];
#pragma unroll
        for (int r = 0; r < 4; ++r)
            t1[(kb * 4 + r) * 136 + tt * 16 + m] = f2us(gelu_f(acc[r] + bv));
    }
    lds_fence();
    short8 f0, f1, f2, f3;
    read_frags(t1, m, kb, f0, f1, f2, f3);
    lds_fence();
    // G4 = gelu(G3@Wf2+bf2), 64 cols -> t1
#pragma unroll
    for (int tt = 0; tt < 4; ++tt) {
        float4v acc = mfma4(Wf + 16384, tt * 16, m, kb, f0, f1, f2, f3);
        float bv = bf2[tt * 16 + m];
#pragma unroll
        for (int r = 0; r < 4; ++r)
            t1[(kb * 4 + r) * 136 + tt * 16 + m] = f2us(gelu_f(acc[r] + bv));
    }
    lds_fence();
    // store 16 rows x 64 cols fp32
#pragma unroll
    for (int it = 0; it < 2; ++it) {
        int j = it * 64 + l;
        int row = j >> 3, col = (j & 7) * 8;
        int grow = r0w + row;
        if (grow < NN) {
            uint4 pk = *(const uint4*)&t1[row * 136 + col];
            const u16* pv = (const u16*)&pk;
            float* po = outp + (size_t)grow * 64 + col;
            float4 o0 = {us2f(pv[0]), us2f(pv[1]), us2f(pv[2]), us2f(pv[3])};
            float4 o1 = {us2f(pv[4]), us2f(pv[5]), us2f(pv[6]), us2f(pv[7])};
            *(float4*)po = o0;
            *(float4*)(po + 4) = o1;
        }
    }
}

// ---------------- TransformerConv aggregation (unchanged from R7) ----------------

__global__ __launch_bounds__(256) void k_conv(const int* __restrict__ rowstart,
                                              const int4* __restrict__ rec,
                                              const u16* __restrict__ qkvs,
                                              const float* __restrict__ We,
                                              u16* __restrict__ out) {
    int n = blockIdx.x * 4 + (threadIdx.x >> 6);
    int l = threadIdx.x & 63;
    int c0 = (l >> 4) * 32 + (l & 15) * 2;
    const u16* qrow = qkvs + (size_t)n * 512;
    u32 qu = *(const u32*)(qrow + c0);
    float q0 = blo(qu), q1 = bhi(qu);
    float we00 = We[c0 * 3 + 0], we01 = We[c0 * 3 + 1], we02 = We[c0 * 3 + 2];
    float we10 = We[c0 * 3 + 3], we11 = We[c0 * 3 + 4], we12 = We[c0 * 3 + 5];
    float g0 = fmaf(q1, we10, q0 * we00);
    float g1 = fmaf(q1, we11, q0 * we01);
    float g2 = fmaf(q1, we12, q0 * we02);
#pragma unroll
    for (int d = 8; d >= 1; d >>= 1) {
        g0 += __shfl_xor(g0, d);
        g1 += __shfl_xor(g1, d);
        g2 += __shfl_xor(g2, d);
    }
    int e0 = rowstart[n], e1 = rowstart[n + 1];
    float ss = 0.f, o0 = 0.f, o1 = 0.f, S0 = 0.f, S1 = 0.f, S2 = 0.f;

    auto edge = [&](int4 r, uint2 kv) {
        float part = fmaf(q1, bhi(kv.x), q0 * blo(kv.x));
        part += __shfl_xor(part, 8);
        part += __shfl_xor(part, 4);
        part += __shfl_xor(part, 2);
        part += __shfl_xor(part, 1);
        float ea0 = __int_as_float(r.y), ea1 = __int_as_float(r.z), ea2 = __int_as_float(r.w);
        float alpha = fmaf(ea2, g2, fmaf(ea1, g1, fmaf(ea0, g0, part))) * 0.17677669529663687f;
        float p = __expf(fminf(alpha, 80.f));
        o0 = fmaf(p, blo(kv.y), o0);
        o1 = fmaf(p, bhi(kv.y), o1);
        ss += p;
        S0 = fmaf(p, ea0, S0);
        S1 = fmaf(p, ea1, S1);
        S2 = fmaf(p, ea2, S2);
    };

    int e = e0;
    if ((e1 - e0) & 1) {
        int4 r = rec[e];
        uint2 kv = *(const uint2*)(qkvs + (size_t)r.x * 512 + 128 + c0 * 2);
        edge(r, kv);
        ++e;
    }
    for (; e < e1; e += 2) {
        int4 ra = rec[e], rb = rec[e + 1];
        uint2 kva = *(const uint2*)(qkvs + (size_t)ra.x * 512 + 128 + c0 * 2);
        uint2 kvb = *(const uint2*)(qkvs + (size_t)rb.x * 512 + 128 + c0 * 2);
        edge(ra, kva);
        edge(rb, kvb);
    }
    float inv = __builtin_amdgcn_rcpf(fmaxf(ss, 1e-16f));
    o0 = fmaf(we02, S2, fmaf(we01, S1, fmaf(we00, S0, o0)));
    o1 = fmaf(we12, S2, fmaf(we11, S1, fmaf(we10, S0, o1)));
    u32 su = *(const u32*)(qrow + 384 + c0);
    float r0v = fmaf(o0, inv, blo(su));
    float r1v = fmaf(o1, inv, bhi(su));
    u32 ou = (u32)f2us(r0v) | ((u32)f2us(r1v) << 16);
    *(u32*)(out + (size_t)n * 128 + c0) = ou;
}

// ---------------- launcher ----------------

extern "C" void kernel_launch(void* const* d_in, const int* in_sizes, int n_in,
                              void* d_out, int out_size, void* d_ws, size_t ws_size,
                              hipStream_t stream) {
    const float* x = (const float*)d_in[0];
    const int* ei = (const int*)d_in[1];
    const float* eattr = (const float*)d_in[2];
    const float* Wq1 = (const float*)d_in[3];
    const float* Wk1 = (const float*)d_in[4];
    const float* Wv1 = (const float*)d_in[5];
    const float* We1 = (const float*)d_in[6];
    const float* Ws1 = (const float*)d_in[7];
    const float* M1a = (const float*)d_in[8];
    const float* b1a = (const float*)d_in[9];
    const float* M1b = (const float*)d_in[10];
    const float* b1b = (const float*)d_in[11];
    const float* Wq2 = (const float*)d_in[12];
    const float* Wk2 = (const float*)d_in[13];
    const float* Wv2 = (const float*)d_in[14];
    const float* We2 = (const float*)d_in[15];
    const float* Ws2 = (const float*)d_in[16];
    const float* M2a = (const float*)d_in[17];
    const float* b2a = (const float*)d_in[18];
    const float* M2b = (const float*)d_in[19];
    const float* b2b = (const float*)d_in[20];
    const float* Wf1 = (const float*)d_in[21];
    const float* bf1 = (const float*)d_in[22];
    const float* Wf2 = (const float*)d_in[23];
    const float* bf2 = (const float*)d_in[24];

    char* ws = (char*)d_ws;
    size_t off = 0;
    auto alloc = [&](size_t bytes) -> void* {
        void* p = ws + off;
        off = (off + bytes + 255) & ~(size_t)255;
        return p;
    };
    int* deg = (int*)alloc((size_t)NN * 4);
    int* rowstart = (int*)alloc((size_t)(NN + 1) * 4);
    int* cursor = (int*)alloc((size_t)NN * 4);
    int* bsum = (int*)alloc((size_t)NB_SCAN * 4);
    int4* rec = (int4*)alloc((size_t)NE * 16);
    u16* QKVS = (u16*)alloc((size_t)NPAD * 512 * 2);
    u16* Ha = (u16*)alloc((size_t)NPAD * 128 * 2);
    // weight order: [Wq1 Wk1 Wv1 Ws1][Wq2 Wk2 Wv2 Ws2][M1a M1b][M2a M2b][Wf1 Wf2]
    u16* WB[14];
    const int wsz[14] = {16384, 16384, 16384, 16384, 16384, 16384, 16384,
                         16384, 16384, 16384, 16384, 16384, 16384, 8192};
    for (int i = 0; i < 14; ++i) WB[i] = (u16*)alloc((size_t)wsz[i] * 2);

    const int* srcv = ei;
    const int* dstv = ei + NE;

    // CSR build
    hipMemsetAsync(deg, 0, (size_t)NN * 4, stream);
    k_hist<<<(NE + 255) / 256, 256, 0, stream>>>(dstv, deg);
    k_scan1<<<NB_SCAN, 256, 0, stream>>>(deg, rowstart, bsum);
    k_scan2<<<1, 256, 0, stream>>>(bsum);
    k_scan3<<<NB_SCAN, 256, 0, stream>>>(bsum, rowstart, cursor);
    k_scatter<<<(NE + 255) / 256, 256, 0, stream>>>(srcv, dstv, eattr, cursor, rec);

    CvtTab tab;
    const float* wsrc[14] = {Wq1, Wk1, Wv1, Ws1, Wq2, Wk2, Wv2, Ws2,
                             M1a, M1b, M2a, M2b, Wf1, Wf2};
    for (int i = 0; i < 14; ++i) { tab.e[i].s = wsrc[i]; tab.e[i].d = WB[i]; tab.e[i].n = wsz[i]; }
    k_cvt_w<<<112, 256, 0, stream>>>(tab);

    dim3 blk(256);
    dim3 grd(NPAD / 64);   // 782
    dim3 gconv(NN / 4);    // 12500

    // layer 1
    k_qkvs1<<<grd, blk, 0, stream>>>(x, WB[0], QKVS);
    k_conv<<<gconv, blk, 0, stream>>>(rowstart, rec, QKVS, We1, Ha);            // H1 = Ha
    // MLP1 + layer-2 QKVS (H2 never hits HBM)
    k_mlp_qkvs<<<grd, blk, 0, stream>>>(Ha, WB[8], b1a, b1b, WB[4], QKVS);
    k_conv<<<gconv, blk, 0, stream>>>(rowstart, rec, QKVS, We2, Ha);            // H3 = Ha
    // MLP2 + final MLP (H4 never hits HBM)
    k_mlp_final<<<grd, blk, 0, stream>>>(Ha, WB[10], b2a, b2b, WB[12], bf1, bf2, (float*)d_out);
}

// Round 9
// 430.875 us; speedup vs baseline: 1.3138x; 1.3138x over previous
//
#include <hip/hip_runtime.h>
#include <hip/hip_bf16.h>
#include <math.h>

// Problem constants (fixed by the reference)
#define NN 50000
#define NE 800000
#define NPAD 50048   // 782 * 64 — tail-free GEMM tiles
#define NB_SCAN 196  // ceil(NN/256)

typedef unsigned short u16;
typedef unsigned int u32;
typedef __attribute__((ext_vector_type(8))) short short8;   // 8 bf16 (MFMA A/B frag)
typedef __attribute__((ext_vector_type(4))) float float4v;  // MFMA C/D frag

__device__ __forceinline__ float us2f(u16 u) { return __uint_as_float(((unsigned)u) << 16); }
__device__ __forceinline__ float blo(u32 u) { return __uint_as_float(u << 16); }
__device__ __forceinline__ float bhi(u32 u) { return __uint_as_float(u & 0xffff0000u); }
__device__ __forceinline__ u16 f2us(float f) {   // fp32 -> bf16 RNE
    unsigned x = __float_as_uint(f);
    return (u16)((x + 0x7FFFu + ((x >> 16) & 1u)) >> 16);
}
// tanh-gelu via sigmoid identity: 0.5*(1+tanh(u)) = sigmoid(2u)
__device__ __forceinline__ float gelu_f(float x) {
    float p = x * x;
    float t = x * fmaf(p, 0.0713548162726f, 1.5957691216057308f);  // 2u
    float e = __expf(-t);
    return x * __builtin_amdgcn_rcpf(1.0f + e);
}
// intra-wave LDS ordering fence (wave-private LDS regions; no cross-wave barrier)
__device__ __forceinline__ void lds_fence() {
    asm volatile("s_waitcnt lgkmcnt(0)" ::: "memory");
}

// ---- permuted-weight MFMA: WP holds B-frags contiguous per (tile, kblock) ----
// WP u16 layout: tile*2048 + q*512 + l*8 + j  <=>  W[tile*16 + (l&15)][q*32 + (l>>4)*8 + j]
// Each load: 64 lanes x 16 B contiguous (single 1 KB burst, wave-uniform address).
__device__ __forceinline__ float4v mfma4p(const u16* __restrict__ WP, int tile, int l,
                                          short8 a0, short8 a1, short8 a2, short8 a3) {
    const short8* wp = (const short8*)WP + (size_t)tile * 256 + l;
    short8 b0 = wp[0], b1 = wp[64], b2 = wp[128], b3 = wp[192];
    float4v acc = {0.f, 0.f, 0.f, 0.f};
    acc = __builtin_amdgcn_mfma_f32_16x16x32_bf16(a0, b0, acc, 0, 0, 0);
    acc = __builtin_amdgcn_mfma_f32_16x16x32_bf16(a1, b1, acc, 0, 0, 0);
    acc = __builtin_amdgcn_mfma_f32_16x16x32_bf16(a2, b2, acc, 0, 0, 0);
    acc = __builtin_amdgcn_mfma_f32_16x16x32_bf16(a3, b3, acc, 0, 0, 0);
    return acc;
}

// ---------------- CSR build ----------------

__global__ void k_hist(const int* __restrict__ dstv, int* __restrict__ deg) {
    int e = blockIdx.x * blockDim.x + threadIdx.x;
    if (e < NE) atomicAdd(&deg[dstv[e]], 1);
}

__global__ __launch_bounds__(256) void k_scan1(const int* __restrict__ deg,
                                               int* __restrict__ rowstart,
                                               int* __restrict__ bsum) {
    __shared__ int wtot[4];
    int i = blockIdx.x * 256 + threadIdx.x;
    int lane = threadIdx.x & 63, w = threadIdx.x >> 6;
    int v = (i < NN) ? deg[i] : 0;
    int incl = v;
#pragma unroll
    for (int d = 1; d < 64; d <<= 1) {
        int tv = __shfl_up(incl, d);
        if (lane >= d) incl += tv;
    }
    if (lane == 63) wtot[w] = incl;
    __syncthreads();
    if (threadIdx.x == 0) {
        int s = 0;
#pragma unroll
        for (int j = 0; j < 4; ++j) { int t = wtot[j]; wtot[j] = s; s += t; }
        bsum[blockIdx.x] = s;
    }
    __syncthreads();
    if (i < NN) rowstart[i] = incl - v + wtot[w];
}

__global__ __launch_bounds__(256) void k_scan2(int* __restrict__ bsum) {
    __shared__ int wtot[4];
    int t = threadIdx.x;
    int lane = t & 63, w = t >> 6;
    int v = (t < NB_SCAN) ? bsum[t] : 0;
    int incl = v;
#pragma unroll
    for (int d = 1; d < 64; d <<= 1) {
        int tv = __shfl_up(incl, d);
        if (lane >= d) incl += tv;
    }
    if (lane == 63) wtot[w] = incl;
    __syncthreads();
    if (t == 0) {
        int s = 0;
#pragma unroll
        for (int j = 0; j < 4; ++j) { int tt = wtot[j]; wtot[j] = s; s += tt; }
    }
    __syncthreads();
    if (t < NB_SCAN) bsum[t] = incl - v + wtot[w];
}

__global__ void k_scan3(const int* __restrict__ bsum, int* __restrict__ rowstart,
                        int* __restrict__ cursor) {
    int i = blockIdx.x * 256 + threadIdx.x;
    if (i < NN) {
        int v = rowstart[i] + bsum[blockIdx.x];
        rowstart[i] = v;
        cursor[i] = v;
    }
    if (i == 0) rowstart[NN] = NE;
}

__global__ void k_scatter(const int* __restrict__ srcv, const int* __restrict__ dstv,
                          const float* __restrict__ eattr, int* __restrict__ cursor,
                          int4* __restrict__ rec) {
    int e = blockIdx.x * blockDim.x + threadIdx.x;
    if (e >= NE) return;
    int dst = dstv[e];
    int pos = atomicAdd(&cursor[dst], 1);
    int4 r;
    r.x = srcv[e];
    r.y = __float_as_int(eattr[e * 3 + 0]);
    r.z = __float_as_int(eattr[e * 3 + 1]);
    r.w = __float_as_int(eattr[e * 3 + 2]);
    rec[pos] = r;
}

// ---------------- weight fp32 -> bf16, permuted into B-frag order ----------------
// dest[o]: tile=o>>11, q=(o>>9)&3, l=(o>>3)&63, j=o&7
//   = src[(tile*16 + (l&15))*128 + q*32 + (l>>4)*8 + j]

struct CvtEnt { const float* s; u16* d; int n; };
struct CvtTab { CvtEnt e[14]; };
__global__ void k_cvt_w(CvtTab tab) {
    CvtEnt E = tab.e[blockIdx.x >> 3];
    int chunk = blockIdx.x & 7;
    int per = E.n >> 3;
    int lo = chunk * per, hi = lo + per;
    for (int o = lo + threadIdx.x; o < hi; o += blockDim.x) {
        int tile = o >> 11;
        int q = (o >> 9) & 3;
        int l = (o >> 3) & 63;
        int j = o & 7;
        int row = tile * 16 + (l & 15);
        int col = q * 32 + (l >> 4) * 8 + j;
        E.d[o] = f2us(E.s[row * 128 + col]);
    }
}

// =============== barrier-free, wave-private GEMM chain kernels ===============

__device__ __forceinline__ void stage_plain(u16* buf, int kb, int m, int tt, float4v acc) {
#pragma unroll
    for (int r = 0; r < 4; ++r) buf[(kb * 4 + r) * 136 + tt * 16 + m] = f2us(acc[r]);
}
__device__ __forceinline__ void store128(const u16* buf, u16* dst, int r0w, int coff, int l) {
#pragma unroll
    for (int it = 0; it < 4; ++it) {
        int j = it * 64 + l;
        int row = j >> 4, col = (j & 15) * 8;
        *(uint4*)(dst + (size_t)(r0w + row) * 512 + coff + col) = *(const uint4*)&buf[row * 136 + col];
    }
}
__device__ __forceinline__ void read_frags(const u16* buf, int m, int kb,
                                           short8& f0, short8& f1, short8& f2, short8& f3) {
    const u16* p = buf + m * 136 + kb * 8;
    f0 = *(const short8*)(p);
    f1 = *(const short8*)(p + 32);
    f2 = *(const short8*)(p + 64);
    f3 = *(const short8*)(p + 96);
}

// ---------------- layer-1 QKVS GEMM (A = fp32 x; W permuted, 32 tiles) ----------------
// QKVS row (stride 512): [q 0..127 | kv interleaved 128..383 | s 384..511]

__global__ __launch_bounds__(256, 4) void k_qkvs1(const float* __restrict__ Ain,
                                                  const u16* __restrict__ W,
                                                  u16* __restrict__ QKVS) {
    __shared__ u16 tile[4][16 * 136];
    int tid = threadIdx.x;
    int l = tid & 63, w = tid >> 6, m = l & 15, kb = l >> 4;
    int r0w = blockIdx.x * 64 + w * 16;
    u16* my = tile[w];

    short8 a0, a1, a2, a3;
    {
        const float* ap = Ain + (size_t)(r0w + m) * 128;
        bool ok = (r0w + m) < NN;
        short8* dsts[4] = {&a0, &a1, &a2, &a3};
#pragma unroll
        for (int i = 0; i < 4; ++i) {
            short8 r;
            if (ok) {
                const float* p = ap + (kb + i * 4) * 8;
                float4 f0 = *(const float4*)p;
                float4 f1 = *(const float4*)(p + 4);
                r[0]=(short)f2us(f0.x); r[1]=(short)f2us(f0.y); r[2]=(short)f2us(f0.z); r[3]=(short)f2us(f0.w);
                r[4]=(short)f2us(f1.x); r[5]=(short)f2us(f1.y); r[6]=(short)f2us(f1.z); r[7]=(short)f2us(f1.w);
            } else {
#pragma unroll
                for (int j = 0; j < 8; ++j) r[j] = 0;
            }
            *dsts[i] = r;
        }
    }

    // ---- q (tiles 0..7) ----
#pragma unroll
    for (int tt = 0; tt < 8; ++tt) stage_plain(my, kb, m, tt, mfma4p(W, tt, l, a0, a1, a2, a3));
    lds_fence();
    store128(my, QKVS, r0w, 0, l);
    lds_fence();
    // ---- kv-lo: k tiles 8..11 + v tiles 16..19 ----
#pragma unroll
    for (int tt = 0; tt < 4; ++tt) {
        float4v acc = mfma4p(W, 8 + tt, l, a0, a1, a2, a3);
        int c = tt * 32 + 4 * (m >> 1) + (m & 1);
#pragma unroll
        for (int r = 0; r < 4; ++r) my[(kb * 4 + r) * 136 + c] = f2us(acc[r]);
    }
#pragma unroll
    for (int tt = 0; tt < 4; ++tt) {
        float4v acc = mfma4p(W, 16 + tt, l, a0, a1, a2, a3);
        int c = tt * 32 + 4 * (m >> 1) + (m & 1) + 2;
#pragma unroll
        for (int r = 0; r < 4; ++r) my[(kb * 4 + r) * 136 + c] = f2us(acc[r]);
    }
    lds_fence();
    store128(my, QKVS, r0w, 128, l);
    lds_fence();
    // ---- kv-hi: k tiles 12..15 + v tiles 20..23 ----
#pragma unroll
    for (int tt = 0; tt < 4; ++tt) {
        float4v acc = mfma4p(W, 12 + tt, l, a0, a1, a2, a3);
        int c = tt * 32 + 4 * (m >> 1) + (m & 1);
#pragma unroll
        for (int r = 0; r < 4; ++r) my[(kb * 4 + r) * 136 + c] = f2us(acc[r]);
    }
#pragma unroll
    for (int tt = 0; tt < 4; ++tt) {
        float4v acc = mfma4p(W, 20 + tt, l, a0, a1, a2, a3);
        int c = tt * 32 + 4 * (m >> 1) + (m & 1) + 2;
#pragma unroll
        for (int r = 0; r < 4; ++r) my[(kb * 4 + r) * 136 + c] = f2us(acc[r]);
    }
    lds_fence();
    store128(my, QKVS, r0w, 256, l);
    lds_fence();
    // ---- s (tiles 24..31) ----
#pragma unroll
    for (int tt = 0; tt < 8; ++tt) stage_plain(my, kb, m, tt, mfma4p(W, 24 + tt, l, a0, a1, a2, a3));
    lds_fence();
    store128(my, QKVS, r0w, 384, l);
}

// ---------------- fused MLP + next-layer QKVS ----------------

__global__ __launch_bounds__(256, 4) void k_mlp_qkvs(const u16* __restrict__ Ain,
                                                     const u16* __restrict__ Wm,
                                                     const float* __restrict__ bias1,
                                                     const float* __restrict__ bias2,
                                                     const u16* __restrict__ Wq,
                                                     u16* __restrict__ QKVS) {
    __shared__ u16 shb[4][16 * 136];
    __shared__ u16 t1b[4][16 * 136];
    int tid = threadIdx.x;
    int l = tid & 63, w = tid >> 6, m = l & 15, kb = l >> 4;
    int r0w = blockIdx.x * 64 + w * 16;
    u16* sh = shb[w];
    u16* t1 = t1b[w];

    const short8* arow = (const short8*)(Ain + (size_t)(r0w + m) * 128);
    short8 a0 = arow[kb], a1 = arow[kb + 4], a2 = arow[kb + 8], a3 = arow[kb + 12];
    {   // stage A (residual source), linear rows
        u16* p = sh + m * 136 + kb * 8;
        *(short8*)(p) = a0;
        *(short8*)(p + 32) = a1;
        *(short8*)(p + 64) = a2;
        *(short8*)(p + 96) = a3;
    }
    // GEMM1 -> t1 (gelu)
#pragma unroll
    for (int tt = 0; tt < 8; ++tt) {
        float4v acc = mfma4p(Wm, tt, l, a0, a1, a2, a3);
        float bv = bias1[tt * 16 + m];
#pragma unroll
        for (int r = 0; r < 4; ++r)
            t1[(kb * 4 + r) * 136 + tt * 16 + m] = f2us(gelu_f(acc[r] + bv));
    }
    lds_fence();
    short8 c0, c1, c2, c3;
    read_frags(t1, m, kb, c0, c1, c2, c3);
    // GEMM2 + residual -> sh becomes H2 (owner-lane RMW)
#pragma unroll
    for (int tt = 0; tt < 8; ++tt) {
        float4v acc = mfma4p(Wm + 16384, tt, l, c0, c1, c2, c3);
        float bv = bias2[tt * 16 + m];
#pragma unroll
        for (int r = 0; r < 4; ++r) {
            int idx = (kb * 4 + r) * 136 + tt * 16 + m;
            sh[idx] = f2us(gelu_f(acc[r] + bv) + us2f(sh[idx]));
        }
    }
    lds_fence();
    short8 h0, h1, h2, h3;
    read_frags(sh, m, kb, h0, h1, h2, h3);

    // ---- q (tiles 0..7) ----
#pragma unroll
    for (int tt = 0; tt < 8; ++tt) stage_plain(t1, kb, m, tt, mfma4p(Wq, tt, l, h0, h1, h2, h3));
    lds_fence();
    store128(t1, QKVS, r0w, 0, l);
    lds_fence();
    // ---- kv-lo ----
#pragma unroll
    for (int tt = 0; tt < 4; ++tt) {
        float4v acc = mfma4p(Wq, 8 + tt, l, h0, h1, h2, h3);
        int c = tt * 32 + 4 * (m >> 1) + (m & 1);
#pragma unroll
        for (int r = 0; r < 4; ++r) t1[(kb * 4 + r) * 136 + c] = f2us(acc[r]);
    }
#pragma unroll
    for (int tt = 0; tt < 4; ++tt) {
        float4v acc = mfma4p(Wq, 16 + tt, l, h0, h1, h2, h3);
        int c = tt * 32 + 4 * (m >> 1) + (m & 1) + 2;
#pragma unroll
        for (int r = 0; r < 4; ++r) t1[(kb * 4 + r) * 136 + c] = f2us(acc[r]);
    }
    lds_fence();
    store128(t1, QKVS, r0w, 128, l);
    lds_fence();
    // ---- kv-hi ----
#pragma unroll
    for (int tt = 0; tt < 4; ++tt) {
        float4v acc = mfma4p(Wq, 12 + tt, l, h0, h1, h2, h3);
        int c = tt * 32 + 4 * (m >> 1) + (m & 1);
#pragma unroll
        for (int r = 0; r < 4; ++r) t1[(kb * 4 + r) * 136 + c] = f2us(acc[r]);
    }
#pragma unroll
    for (int tt = 0; tt < 4; ++tt) {
        float4v acc = mfma4p(Wq, 20 + tt, l, h0, h1, h2, h3);
        int c = tt * 32 + 4 * (m >> 1) + (m & 1) + 2;
#pragma unroll
        for (int r = 0; r < 4; ++r) t1[(kb * 4 + r) * 136 + c] = f2us(acc[r]);
    }
    lds_fence();
    store128(t1, QKVS, r0w, 256, l);
    lds_fence();
    // ---- s (tiles 24..31) ----
#pragma unroll
    for (int tt = 0; tt < 8; ++tt) stage_plain(t1, kb, m, tt, mfma4p(Wq, 24 + tt, l, h0, h1, h2, h3));
    lds_fence();
    store128(t1, QKVS, r0w, 384, l);
}

// ---------------- fused MLP + final MLP ----------------

__global__ __launch_bounds__(256, 4) void k_mlp_final(const u16* __restrict__ Ain,
                                                      const u16* __restrict__ Wm,
                                                      const float* __restrict__ bias1,
                                                      const float* __restrict__ bias2,
                                                      const u16* __restrict__ Wf,
                                                      const float* __restrict__ bf1,
                                                      const float* __restrict__ bf2,
                                                      float* __restrict__ outp) {
    __shared__ u16 shb[4][16 * 136];
    __shared__ u16 t1b[4][16 * 136];
    int tid = threadIdx.x;
    int l = tid & 63, w = tid >> 6, m = l & 15, kb = l >> 4;
    int r0w = blockIdx.x * 64 + w * 16;
    u16* sh = shb[w];
    u16* t1 = t1b[w];

    const short8* arow = (const short8*)(Ain + (size_t)(r0w + m) * 128);
    short8 a0 = arow[kb], a1 = arow[kb + 4], a2 = arow[kb + 8], a3 = arow[kb + 12];
    {
        u16* p = sh + m * 136 + kb * 8;
        *(short8*)(p) = a0;
        *(short8*)(p + 32) = a1;
        *(short8*)(p + 64) = a2;
        *(short8*)(p + 96) = a3;
    }
#pragma unroll
    for (int tt = 0; tt < 8; ++tt) {
        float4v acc = mfma4p(Wm, tt, l, a0, a1, a2, a3);
        float bv = bias1[tt * 16 + m];
#pragma unroll
        for (int r = 0; r < 4; ++r)
            t1[(kb * 4 + r) * 136 + tt * 16 + m] = f2us(gelu_f(acc[r] + bv));
    }
    lds_fence();
    short8 c0, c1, c2, c3;
    read_frags(t1, m, kb, c0, c1, c2, c3);
#pragma unroll
    for (int tt = 0; tt < 8; ++tt) {
        float4v acc = mfma4p(Wm + 16384, tt, l, c0, c1, c2, c3);
        float bv = bias2[tt * 16 + m];
#pragma unroll
        for (int r = 0; r < 4; ++r) {
            int idx = (kb * 4 + r) * 136 + tt * 16 + m;
            sh[idx] = f2us(gelu_f(acc[r] + bv) + us2f(sh[idx]));
        }
    }
    lds_fence();
    short8 h0, h1, h2, h3;
    read_frags(sh, m, kb, h0, h1, h2, h3);
    // G3 = gelu(H4@Wf1+bf1) -> t1
#pragma unroll
    for (int tt = 0; tt < 8; ++tt) {
        float4v acc = mfma4p(Wf, tt, l, h0, h1, h2, h3);
        float bv = bf1[tt * 16 + m];
#pragma unroll
        for (int r = 0; r < 4; ++r)
            t1[(kb * 4 + r) * 136 + tt * 16 + m] = f2us(gelu_f(acc[r] + bv));
    }
    lds_fence();
    short8 f0, f1, f2, f3;
    read_frags(t1, m, kb, f0, f1, f2, f3);
    lds_fence();
    // G4 = gelu(G3@Wf2+bf2), 64 cols -> t1
#pragma unroll
    for (int tt = 0; tt < 4; ++tt) {
        float4v acc = mfma4p(Wf + 16384, tt, l, f0, f1, f2, f3);
        float bv = bf2[tt * 16 + m];
#pragma unroll
        for (int r = 0; r < 4; ++r)
            t1[(kb * 4 + r) * 136 + tt * 16 + m] = f2us(gelu_f(acc[r] + bv));
    }
    lds_fence();
#pragma unroll
    for (int it = 0; it < 2; ++it) {
        int j = it * 64 + l;
        int row = j >> 3, col = (j & 7) * 8;
        int grow = r0w + row;
        if (grow < NN) {
            uint4 pk = *(const uint4*)&t1[row * 136 + col];
            const u16* pv = (const u16*)&pk;
            float* po = outp + (size_t)grow * 64 + col;
            float4 o0 = {us2f(pv[0]), us2f(pv[1]), us2f(pv[2]), us2f(pv[3])};
            float4 o1 = {us2f(pv[4]), us2f(pv[5]), us2f(pv[6]), us2f(pv[7])};
            *(float4*)po = o0;
            *(float4*)(po + 4) = o1;
        }
    }
}

// ---------------- TransformerConv aggregation (unchanged) ----------------

__global__ __launch_bounds__(256) void k_conv(const int* __restrict__ rowstart,
                                              const int4* __restrict__ rec,
                                              const u16* __restrict__ qkvs,
                                              const float* __restrict__ We,
                                              u16* __restrict__ out) {
    int n = blockIdx.x * 4 + (threadIdx.x >> 6);
    int l = threadIdx.x & 63;
    int c0 = (l >> 4) * 32 + (l & 15) * 2;
    const u16* qrow = qkvs + (size_t)n * 512;
    u32 qu = *(const u32*)(qrow + c0);
    float q0 = blo(qu), q1 = bhi(qu);
    float we00 = We[c0 * 3 + 0], we01 = We[c0 * 3 + 1], we02 = We[c0 * 3 + 2];
    float we10 = We[c0 * 3 + 3], we11 = We[c0 * 3 + 4], we12 = We[c0 * 3 + 5];
    float g0 = fmaf(q1, we10, q0 * we00);
    float g1 = fmaf(q1, we11, q0 * we01);
    float g2 = fmaf(q1, we12, q0 * we02);
#pragma unroll
    for (int d = 8; d >= 1; d >>= 1) {
        g0 += __shfl_xor(g0, d);
        g1 += __shfl_xor(g1, d);
        g2 += __shfl_xor(g2, d);
    }
    int e0 = rowstart[n], e1 = rowstart[n + 1];
    float ss = 0.f, o0 = 0.f, o1 = 0.f, S0 = 0.f, S1 = 0.f, S2 = 0.f;

    auto edge = [&](int4 r, uint2 kv) {
        float part = fmaf(q1, bhi(kv.x), q0 * blo(kv.x));
        part += __shfl_xor(part, 8);
        part += __shfl_xor(part, 4);
        part += __shfl_xor(part, 2);
        part += __shfl_xor(part, 1);
        float ea0 = __int_as_float(r.y), ea1 = __int_as_float(r.z), ea2 = __int_as_float(r.w);
        float alpha = fmaf(ea2, g2, fmaf(ea1, g1, fmaf(ea0, g0, part))) * 0.17677669529663687f;
        float p = __expf(fminf(alpha, 80.f));
        o0 = fmaf(p, blo(kv.y), o0);
        o1 = fmaf(p, bhi(kv.y), o1);
        ss += p;
        S0 = fmaf(p, ea0, S0);
        S1 = fmaf(p, ea1, S1);
        S2 = fmaf(p, ea2, S2);
    };

    int e = e0;
    if ((e1 - e0) & 1) {
        int4 r = rec[e];
        uint2 kv = *(const uint2*)(qkvs + (size_t)r.x * 512 + 128 + c0 * 2);
        edge(r, kv);
        ++e;
    }
    for (; e < e1; e += 2) {
        int4 ra = rec[e], rb = rec[e + 1];
        uint2 kva = *(const uint2*)(qkvs + (size_t)ra.x * 512 + 128 + c0 * 2);
        uint2 kvb = *(const uint2*)(qkvs + (size_t)rb.x * 512 + 128 + c0 * 2);
        edge(ra, kva);
        edge(rb, kvb);
    }
    float inv = __builtin_amdgcn_rcpf(fmaxf(ss, 1e-16f));
    o0 = fmaf(we02, S2, fmaf(we01, S1, fmaf(we00, S0, o0)));
    o1 = fmaf(we12, S2, fmaf(we11, S1, fmaf(we10, S0, o1)));
    u32 su = *(const u32*)(qrow + 384 + c0);
    float r0v = fmaf(o0, inv, blo(su));
    float r1v = fmaf(o1, inv, bhi(su));
    u32 ou = (u32)f2us(r0v) | ((u32)f2us(r1v) << 16);
    *(u32*)(out + (size_t)n * 128 + c0) = ou;
}

// ---------------- launcher ----------------

extern "C" void kernel_launch(void* const* d_in, const int* in_sizes, int n_in,
                              void* d_out, int out_size, void* d_ws, size_t ws_size,
                              hipStream_t stream) {
    const float* x = (const float*)d_in[0];
    const int* ei = (const int*)d_in[1];
    const float* eattr = (const float*)d_in[2];
    const float* Wq1 = (const float*)d_in[3];
    const float* Wk1 = (const float*)d_in[4];
    const float* Wv1 = (const float*)d_in[5];
    const float* We1 = (const float*)d_in[6];
    const float* Ws1 = (const float*)d_in[7];
    const float* M1a = (const float*)d_in[8];
    const float* b1a = (const float*)d_in[9];
    const float* M1b = (const float*)d_in[10];
    const float* b1b = (const float*)d_in[11];
    const float* Wq2 = (const float*)d_in[12];
    const float* Wk2 = (const float*)d_in[13];
    const float* Wv2 = (const float*)d_in[14];
    const float* We2 = (const float*)d_in[15];
    const float* Ws2 = (const float*)d_in[16];
    const float* M2a = (const float*)d_in[17];
    const float* b2a = (const float*)d_in[18];
    const float* M2b = (const float*)d_in[19];
    const float* b2b = (const float*)d_in[20];
    const float* Wf1 = (const float*)d_in[21];
    const float* bf1 = (const float*)d_in[22];
    const float* Wf2 = (const float*)d_in[23];
    const float* bf2 = (const float*)d_in[24];

    char* ws = (char*)d_ws;
    size_t off = 0;
    auto alloc = [&](size_t bytes) -> void* {
        void* p = ws + off;
        off = (off + bytes + 255) & ~(size_t)255;
        return p;
    };
    int* deg = (int*)alloc((size_t)NN * 4);
    int* rowstart = (int*)alloc((size_t)(NN + 1) * 4);
    int* cursor = (int*)alloc((size_t)NN * 4);
    int* bsum = (int*)alloc((size_t)NB_SCAN * 4);
    int4* rec = (int4*)alloc((size_t)NE * 16);
    u16* QKVS = (u16*)alloc((size_t)NPAD * 512 * 2);
    u16* Ha = (u16*)alloc((size_t)NPAD * 128 * 2);
    // weight order: [Wq1 Wk1 Wv1 Ws1][Wq2 Wk2 Wv2 Ws2][M1a M1b][M2a M2b][Wf1 Wf2]
    u16* WB[14];
    const int wsz[14] = {16384, 16384, 16384, 16384, 16384, 16384, 16384,
                         16384, 16384, 16384, 16384, 16384, 16384, 8192};
    for (int i = 0; i < 14; ++i) WB[i] = (u16*)alloc((size_t)wsz[i] * 2);

    const int* srcv = ei;
    const int* dstv = ei + NE;

    // CSR build
    hipMemsetAsync(deg, 0, (size_t)NN * 4, stream);
    k_hist<<<(NE + 255) / 256, 256, 0, stream>>>(dstv, deg);
    k_scan1<<<NB_SCAN, 256, 0, stream>>>(deg, rowstart, bsum);
    k_scan2<<<1, 256, 0, stream>>>(bsum);
    k_scan3<<<NB_SCAN, 256, 0, stream>>>(bsum, rowstart, cursor);
    k_scatter<<<(NE + 255) / 256, 256, 0, stream>>>(srcv, dstv, eattr, cursor, rec);

    CvtTab tab;
    const float* wsrc[14] = {Wq1, Wk1, Wv1, Ws1, Wq2, Wk2, Wv2, Ws2,
                             M1a, M1b, M2a, M2b, Wf1, Wf2};
    for (int i = 0; i < 14; ++i) { tab.e[i].s = wsrc[i]; tab.e[i].d = WB[i]; tab.e[i].n = wsz[i]; }
    k_cvt_w<<<112, 256, 0, stream>>>(tab);

    dim3 blk(256);
    dim3 grd(NPAD / 64);   // 782
    dim3 gconv(NN / 4);    // 12500

    // layer 1
    k_qkvs1<<<grd, blk, 0, stream>>>(x, WB[0], QKVS);
    k_conv<<<gconv, blk, 0, stream>>>(rowstart, rec, QKVS, We1, Ha);            // H1 = Ha
    // MLP1 + layer-2 QKVS (H2 never hits HBM)
    k_mlp_qkvs<<<grd, blk, 0, stream>>>(Ha, WB[8], b1a, b1b, WB[4], QKVS);
    k_conv<<<gconv, blk, 0, stream>>>(rowstart, rec, QKVS, We2, Ha);            // H3 = Ha
    // MLP2 + final MLP (H4 never hits HBM)
    k_mlp_final<<<grd, blk, 0, stream>>>(Ha, WB[10], b2a, b2b, WB[12], bf1, bf2, (float*)d_out);
}

// Round 10
// 410.063 us; speedup vs baseline: 1.3805x; 1.0508x over previous
//
#include <hip/hip_runtime.h>
#include <hip/hip_bf16.h>
#include <math.h>

// Problem constants (fixed by the reference)
#define NN 50000
#define NE 800000
#define NPAD 50048   // 782 * 64 — tail-free GEMM tiles
#define NB_SCAN 196  // ceil(NN/256)

typedef unsigned short u16;
typedef unsigned int u32;
typedef __attribute__((ext_vector_type(8))) short short8;   // 8 bf16 (MFMA A/B frag)
typedef __attribute__((ext_vector_type(4))) float float4v;  // MFMA C/D frag

__device__ __forceinline__ float us2f(u16 u) { return __uint_as_float(((unsigned)u) << 16); }
__device__ __forceinline__ float blo(u32 u) { return __uint_as_float(u << 16); }
__device__ __forceinline__ float bhi(u32 u) { return __uint_as_float(u & 0xffff0000u); }
__device__ __forceinline__ u16 f2us(float f) {   // fp32 -> bf16 RNE
    unsigned x = __float_as_uint(f);
    return (u16)((x + 0x7FFFu + ((x >> 16) & 1u)) >> 16);
}
// tanh-gelu via sigmoid identity: 0.5*(1+tanh(u)) = sigmoid(2u)
__device__ __forceinline__ float gelu_f(float x) {
    float p = x * x;
    float t = x * fmaf(p, 0.0713548162726f, 1.5957691216057308f);  // 2u
    float e = __expf(-t);
    return x * __builtin_amdgcn_rcpf(1.0f + e);
}
// intra-wave LDS ordering fence (wave-private LDS regions; no cross-wave barrier)
__device__ __forceinline__ void lds_fence() {
    asm volatile("s_waitcnt lgkmcnt(0)" ::: "memory");
}

// ---- permuted-weight MFMA: WP holds B-frags contiguous per (tile, kblock) ----
// WP u16 layout: tile*2048 + q*512 + l*8 + j  <=>  W[tile*16 + (l&15)][q*32 + (l>>4)*8 + j]
__device__ __forceinline__ float4v mfma4p(const u16* __restrict__ WP, int tile, int l,
                                          short8 a0, short8 a1, short8 a2, short8 a3) {
    const short8* wp = (const short8*)WP + (size_t)tile * 256 + l;
    short8 b0 = wp[0], b1 = wp[64], b2 = wp[128], b3 = wp[192];
    float4v acc = {0.f, 0.f, 0.f, 0.f};
    acc = __builtin_amdgcn_mfma_f32_16x16x32_bf16(a0, b0, acc, 0, 0, 0);
    acc = __builtin_amdgcn_mfma_f32_16x16x32_bf16(a1, b1, acc, 0, 0, 0);
    acc = __builtin_amdgcn_mfma_f32_16x16x32_bf16(a2, b2, acc, 0, 0, 0);
    acc = __builtin_amdgcn_mfma_f32_16x16x32_bf16(a3, b3, acc, 0, 0, 0);
    return acc;
}

// ---------------- CSR build ----------------

__global__ void k_hist(const int* __restrict__ dstv, int* __restrict__ deg) {
    int e = blockIdx.x * blockDim.x + threadIdx.x;
    if (e < NE) atomicAdd(&deg[dstv[e]], 1);
}

__global__ __launch_bounds__(256) void k_scan1(const int* __restrict__ deg,
                                               int* __restrict__ rowstart,
                                               int* __restrict__ bsum) {
    __shared__ int wtot[4];
    int i = blockIdx.x * 256 + threadIdx.x;
    int lane = threadIdx.x & 63, w = threadIdx.x >> 6;
    int v = (i < NN) ? deg[i] : 0;
    int incl = v;
#pragma unroll
    for (int d = 1; d < 64; d <<= 1) {
        int tv = __shfl_up(incl, d);
        if (lane >= d) incl += tv;
    }
    if (lane == 63) wtot[w] = incl;
    __syncthreads();
    if (threadIdx.x == 0) {
        int s = 0;
#pragma unroll
        for (int j = 0; j < 4; ++j) { int t = wtot[j]; wtot[j] = s; s += t; }
        bsum[blockIdx.x] = s;
    }
    __syncthreads();
    if (i < NN) rowstart[i] = incl - v + wtot[w];
}

__global__ __launch_bounds__(256) void k_scan2(int* __restrict__ bsum) {
    __shared__ int wtot[4];
    int t = threadIdx.x;
    int lane = t & 63, w = t >> 6;
    int v = (t < NB_SCAN) ? bsum[t] : 0;
    int incl = v;
#pragma unroll
    for (int d = 1; d < 64; d <<= 1) {
        int tv = __shfl_up(incl, d);
        if (lane >= d) incl += tv;
    }
    if (lane == 63) wtot[w] = incl;
    __syncthreads();
    if (t == 0) {
        int s = 0;
#pragma unroll
        for (int j = 0; j < 4; ++j) { int tt = wtot[j]; wtot[j] = s; s += tt; }
    }
    __syncthreads();
    if (t < NB_SCAN) bsum[t] = incl - v + wtot[w];
}

__global__ void k_scan3(const int* __restrict__ bsum, int* __restrict__ rowstart,
                        int* __restrict__ cursor) {
    int i = blockIdx.x * 256 + threadIdx.x;
    if (i < NN) {
        int v = rowstart[i] + bsum[blockIdx.x];
        rowstart[i] = v;
        cursor[i] = v;
    }
    if (i == 0) rowstart[NN] = NE;
}

__global__ void k_scatter(const int* __restrict__ srcv, const int* __restrict__ dstv,
                          const float* __restrict__ eattr, int* __restrict__ cursor,
                          int4* __restrict__ rec) {
    int e = blockIdx.x * blockDim.x + threadIdx.x;
    if (e >= NE) return;
    int dst = dstv[e];
    int pos = atomicAdd(&cursor[dst], 1);
    int4 r;
    r.x = srcv[e];
    r.y = __float_as_int(eattr[e * 3 + 0]);
    r.z = __float_as_int(eattr[e * 3 + 1]);
    r.w = __float_as_int(eattr[e * 3 + 2]);
    rec[pos] = r;
}

// ---------------- weight fp32 -> bf16, permuted into B-frag order ----------------

struct CvtEnt { const float* s; u16* d; int n; };
struct CvtTab { CvtEnt e[14]; };
__global__ void k_cvt_w(CvtTab tab) {
    CvtEnt E = tab.e[blockIdx.x >> 3];
    int chunk = blockIdx.x & 7;
    int per = E.n >> 3;
    int lo = chunk * per, hi = lo + per;
    for (int o = lo + threadIdx.x; o < hi; o += blockDim.x) {
        int tile = o >> 11;
        int q = (o >> 9) & 3;
        int l = (o >> 3) & 63;
        int j = o & 7;
        int row = tile * 16 + (l & 15);
        int col = q * 32 + (l >> 4) * 8 + j;
        E.d[o] = f2us(E.s[row * 128 + col]);
    }
}

// =============== barrier-free, wave-private GEMM chain kernels ===============

__device__ __forceinline__ void stage_plain(u16* buf, int kb, int m, int tt, float4v acc) {
#pragma unroll
    for (int r = 0; r < 4; ++r) buf[(kb * 4 + r) * 136 + tt * 16 + m] = f2us(acc[r]);
}
__device__ __forceinline__ void store128(const u16* buf, u16* dst, int r0w, int coff, int l) {
#pragma unroll
    for (int it = 0; it < 4; ++it) {
        int j = it * 64 + l;
        int row = j >> 4, col = (j & 15) * 8;
        *(uint4*)(dst + (size_t)(r0w + row) * 512 + coff + col) = *(const uint4*)&buf[row * 136 + col];
    }
}
__device__ __forceinline__ void read_frags(const u16* buf, int m, int kb,
                                           short8& f0, short8& f1, short8& f2, short8& f3) {
    const u16* p = buf + m * 136 + kb * 8;
    f0 = *(const short8*)(p);
    f1 = *(const short8*)(p + 32);
    f2 = *(const short8*)(p + 64);
    f3 = *(const short8*)(p + 96);
}

// ---------------- layer-1 QKVS GEMM (A = fp32 x; W permuted, 32 tiles) ----------------
// QKVS row (stride 512 u16): [q 0..127 | kv 128..383 | s 384..511]
// kv entry layout: for col c, k[c] at (c>>2)*8+(c&3), v[c] at (c>>2)*8+4+(c&3)
// (i.e. groups of {k[4p..4p+3], v[4p..4p+3]} — one dwordx4 per lane in conv).

__global__ __launch_bounds__(256, 4) void k_qkvs1(const float* __restrict__ Ain,
                                                  const u16* __restrict__ W,
                                                  u16* __restrict__ QKVS) {
    __shared__ u16 tile[4][16 * 136];
    int tid = threadIdx.x;
    int l = tid & 63, w = tid >> 6, m = l & 15, kb = l >> 4;
    int r0w = blockIdx.x * 64 + w * 16;
    u16* my = tile[w];

    short8 a0, a1, a2, a3;
    {
        const float* ap = Ain + (size_t)(r0w + m) * 128;
        bool ok = (r0w + m) < NN;
        short8* dsts[4] = {&a0, &a1, &a2, &a3};
#pragma unroll
        for (int i = 0; i < 4; ++i) {
            short8 r;
            if (ok) {
                const float* p = ap + (kb + i * 4) * 8;
                float4 f0 = *(const float4*)p;
                float4 f1 = *(const float4*)(p + 4);
                r[0]=(short)f2us(f0.x); r[1]=(short)f2us(f0.y); r[2]=(short)f2us(f0.z); r[3]=(short)f2us(f0.w);
                r[4]=(short)f2us(f1.x); r[5]=(short)f2us(f1.y); r[6]=(short)f2us(f1.z); r[7]=(short)f2us(f1.w);
            } else {
#pragma unroll
                for (int j = 0; j < 8; ++j) r[j] = 0;
            }
            *dsts[i] = r;
        }
    }

    // ---- q (tiles 0..7) ----
#pragma unroll
    for (int tt = 0; tt < 8; ++tt) stage_plain(my, kb, m, tt, mfma4p(W, tt, l, a0, a1, a2, a3));
    lds_fence();
    store128(my, QKVS, r0w, 0, l);
    lds_fence();
    // ---- kv-lo: k tiles 8..11 + v tiles 16..19 ----
#pragma unroll
    for (int tt = 0; tt < 4; ++tt) {
        float4v acc = mfma4p(W, 8 + tt, l, a0, a1, a2, a3);
        int c = tt * 32 + 8 * (m >> 2) + (m & 3);
#pragma unroll
        for (int r = 0; r < 4; ++r) my[(kb * 4 + r) * 136 + c] = f2us(acc[r]);
    }
#pragma unroll
    for (int tt = 0; tt < 4; ++tt) {
        float4v acc = mfma4p(W, 16 + tt, l, a0, a1, a2, a3);
        int c = tt * 32 + 8 * (m >> 2) + (m & 3) + 4;
#pragma unroll
        for (int r = 0; r < 4; ++r) my[(kb * 4 + r) * 136 + c] = f2us(acc[r]);
    }
    lds_fence();
    store128(my, QKVS, r0w, 128, l);
    lds_fence();
    // ---- kv-hi: k tiles 12..15 + v tiles 20..23 ----
#pragma unroll
    for (int tt = 0; tt < 4; ++tt) {
        float4v acc = mfma4p(W, 12 + tt, l, a0, a1, a2, a3);
        int c = tt * 32 + 8 * (m >> 2) + (m & 3);
#pragma unroll
        for (int r = 0; r < 4; ++r) my[(kb * 4 + r) * 136 + c] = f2us(acc[r]);
    }
#pragma unroll
    for (int tt = 0; tt < 4; ++tt) {
        float4v acc = mfma4p(W, 20 + tt, l, a0, a1, a2, a3);
        int c = tt * 32 + 8 * (m >> 2) + (m & 3) + 4;
#pragma unroll
        for (int r = 0; r < 4; ++r) my[(kb * 4 + r) * 136 + c] = f2us(acc[r]);
    }
    lds_fence();
    store128(my, QKVS, r0w, 256, l);
    lds_fence();
    // ---- s (tiles 24..31) ----
#pragma unroll
    for (int tt = 0; tt < 8; ++tt) stage_plain(my, kb, m, tt, mfma4p(W, 24 + tt, l, a0, a1, a2, a3));
    lds_fence();
    store128(my, QKVS, r0w, 384, l);
}

// ---------------- fused MLP + next-layer QKVS ----------------

__global__ __launch_bounds__(256, 4) void k_mlp_qkvs(const u16* __restrict__ Ain,
                                                     const u16* __restrict__ Wm,
                                                     const float* __restrict__ bias1,
                                                     const float* __restrict__ bias2,
                                                     const u16* __restrict__ Wq,
                                                     u16* __restrict__ QKVS) {
    __shared__ u16 shb[4][16 * 136];
    __shared__ u16 t1b[4][16 * 136];
    int tid = threadIdx.x;
    int l = tid & 63, w = tid >> 6, m = l & 15, kb = l >> 4;
    int r0w = blockIdx.x * 64 + w * 16;
    u16* sh = shb[w];
    u16* t1 = t1b[w];

    const short8* arow = (const short8*)(Ain + (size_t)(r0w + m) * 128);
    short8 a0 = arow[kb], a1 = arow[kb + 4], a2 = arow[kb + 8], a3 = arow[kb + 12];
    {   // stage A (residual source), linear rows
        u16* p = sh + m * 136 + kb * 8;
        *(short8*)(p) = a0;
        *(short8*)(p + 32) = a1;
        *(short8*)(p + 64) = a2;
        *(short8*)(p + 96) = a3;
    }
    // GEMM1 -> t1 (gelu)
#pragma unroll
    for (int tt = 0; tt < 8; ++tt) {
        float4v acc = mfma4p(Wm, tt, l, a0, a1, a2, a3);
        float bv = bias1[tt * 16 + m];
#pragma unroll
        for (int r = 0; r < 4; ++r)
            t1[(kb * 4 + r) * 136 + tt * 16 + m] = f2us(gelu_f(acc[r] + bv));
    }
    lds_fence();
    short8 c0, c1, c2, c3;
    read_frags(t1, m, kb, c0, c1, c2, c3);
    // GEMM2 + residual -> sh becomes H2 (owner-lane RMW)
#pragma unroll
    for (int tt = 0; tt < 8; ++tt) {
        float4v acc = mfma4p(Wm + 16384, tt, l, c0, c1, c2, c3);
        float bv = bias2[tt * 16 + m];
#pragma unroll
        for (int r = 0; r < 4; ++r) {
            int idx = (kb * 4 + r) * 136 + tt * 16 + m;
            sh[idx] = f2us(gelu_f(acc[r] + bv) + us2f(sh[idx]));
        }
    }
    lds_fence();
    short8 h0, h1, h2, h3;
    read_frags(sh, m, kb, h0, h1, h2, h3);

    // ---- q (tiles 0..7) ----
#pragma unroll
    for (int tt = 0; tt < 8; ++tt) stage_plain(t1, kb, m, tt, mfma4p(Wq, tt, l, h0, h1, h2, h3));
    lds_fence();
    store128(t1, QKVS, r0w, 0, l);
    lds_fence();
    // ---- kv-lo ----
#pragma unroll
    for (int tt = 0; tt < 4; ++tt) {
        float4v acc = mfma4p(Wq, 8 + tt, l, h0, h1, h2, h3);
        int c = tt * 32 + 8 * (m >> 2) + (m & 3);
#pragma unroll
        for (int r = 0; r < 4; ++r) t1[(kb * 4 + r) * 136 + c] = f2us(acc[r]);
    }
#pragma unroll
    for (int tt = 0; tt < 4; ++tt) {
        float4v acc = mfma4p(Wq, 16 + tt, l, h0, h1, h2, h3);
        int c = tt * 32 + 8 * (m >> 2) + (m & 3) + 4;
#pragma unroll
        for (int r = 0; r < 4; ++r) t1[(kb * 4 + r) * 136 + c] = f2us(acc[r]);
    }
    lds_fence();
    store128(t1, QKVS, r0w, 128, l);
    lds_fence();
    // ---- kv-hi ----
#pragma unroll
    for (int tt = 0; tt < 4; ++tt) {
        float4v acc = mfma4p(Wq, 12 + tt, l, h0, h1, h2, h3);
        int c = tt * 32 + 8 * (m >> 2) + (m & 3);
#pragma unroll
        for (int r = 0; r < 4; ++r) t1[(kb * 4 + r) * 136 + c] = f2us(acc[r]);
    }
#pragma unroll
    for (int tt = 0; tt < 4; ++tt) {
        float4v acc = mfma4p(Wq, 20 + tt, l, h0, h1, h2, h3);
        int c = tt * 32 + 8 * (m >> 2) + (m & 3) + 4;
#pragma unroll
        for (int r = 0; r < 4; ++r) t1[(kb * 4 + r) * 136 + c] = f2us(acc[r]);
    }
    lds_fence();
    store128(t1, QKVS, r0w, 256, l);
    lds_fence();
    // ---- s (tiles 24..31) ----
#pragma unroll
    for (int tt = 0; tt < 8; ++tt) stage_plain(t1, kb, m, tt, mfma4p(Wq, 24 + tt, l, h0, h1, h2, h3));
    lds_fence();
    store128(t1, QKVS, r0w, 384, l);
}

// ---------------- fused MLP + final MLP ----------------

__global__ __launch_bounds__(256, 4) void k_mlp_final(const u16* __restrict__ Ain,
                                                      const u16* __restrict__ Wm,
                                                      const float* __restrict__ bias1,
                                                      const float* __restrict__ bias2,
                                                      const u16* __restrict__ Wf,
                                                      const float* __restrict__ bf1,
                                                      const float* __restrict__ bf2,
                                                      float* __restrict__ outp) {
    __shared__ u16 shb[4][16 * 136];
    __shared__ u16 t1b[4][16 * 136];
    int tid = threadIdx.x;
    int l = tid & 63, w = tid >> 6, m = l & 15, kb = l >> 4;
    int r0w = blockIdx.x * 64 + w * 16;
    u16* sh = shb[w];
    u16* t1 = t1b[w];

    const short8* arow = (const short8*)(Ain + (size_t)(r0w + m) * 128);
    short8 a0 = arow[kb], a1 = arow[kb + 4], a2 = arow[kb + 8], a3 = arow[kb + 12];
    {
        u16* p = sh + m * 136 + kb * 8;
        *(short8*)(p) = a0;
        *(short8*)(p + 32) = a1;
        *(short8*)(p + 64) = a2;
        *(short8*)(p + 96) = a3;
    }
#pragma unroll
    for (int tt = 0; tt < 8; ++tt) {
        float4v acc = mfma4p(Wm, tt, l, a0, a1, a2, a3);
        float bv = bias1[tt * 16 + m];
#pragma unroll
        for (int r = 0; r < 4; ++r)
            t1[(kb * 4 + r) * 136 + tt * 16 + m] = f2us(gelu_f(acc[r] + bv));
    }
    lds_fence();
    short8 c0, c1, c2, c3;
    read_frags(t1, m, kb, c0, c1, c2, c3);
#pragma unroll
    for (int tt = 0; tt < 8; ++tt) {
        float4v acc = mfma4p(Wm + 16384, tt, l, c0, c1, c2, c3);
        float bv = bias2[tt * 16 + m];
#pragma unroll
        for (int r = 0; r < 4; ++r) {
            int idx = (kb * 4 + r) * 136 + tt * 16 + m;
            sh[idx] = f2us(gelu_f(acc[r] + bv) + us2f(sh[idx]));
        }
    }
    lds_fence();
    short8 h0, h1, h2, h3;
    read_frags(sh, m, kb, h0, h1, h2, h3);
    // G3 = gelu(H4@Wf1+bf1) -> t1
#pragma unroll
    for (int tt = 0; tt < 8; ++tt) {
        float4v acc = mfma4p(Wf, tt, l, h0, h1, h2, h3);
        float bv = bf1[tt * 16 + m];
#pragma unroll
        for (int r = 0; r < 4; ++r)
            t1[(kb * 4 + r) * 136 + tt * 16 + m] = f2us(gelu_f(acc[r] + bv));
    }
    lds_fence();
    short8 f0, f1, f2, f3;
    read_frags(t1, m, kb, f0, f1, f2, f3);
    lds_fence();
    // G4 = gelu(G3@Wf2+bf2), 64 cols -> t1
#pragma unroll
    for (int tt = 0; tt < 4; ++tt) {
        float4v acc = mfma4p(Wf + 16384, tt, l, f0, f1, f2, f3);
        float bv = bf2[tt * 16 + m];
#pragma unroll
        for (int r = 0; r < 4; ++r)
            t1[(kb * 4 + r) * 136 + tt * 16 + m] = f2us(gelu_f(acc[r] + bv));
    }
    lds_fence();
#pragma unroll
    for (int it = 0; it < 2; ++it) {
        int j = it * 64 + l;
        int row = j >> 3, col = (j & 7) * 8;
        int grow = r0w + row;
        if (grow < NN) {
            uint4 pk = *(const uint4*)&t1[row * 136 + col];
            const u16* pv = (const u16*)&pk;
            float* po = outp + (size_t)grow * 64 + col;
            float4 o0 = {us2f(pv[0]), us2f(pv[1]), us2f(pv[2]), us2f(pv[3])};
            float4 o1 = {us2f(pv[4]), us2f(pv[5]), us2f(pv[6]), us2f(pv[7])};
            *(float4*)po = o0;
            *(float4*)(po + 4) = o1;
        }
    }
}

// ---------------- TransformerConv aggregation: 2 edges/wave, 4 cols/lane ----------------
// 1 wave per node (4 nodes/block). Lanes 0-31 handle even-offset edges, 32-63 odd.
// Lane li: head=li>>3, group p4=li&7 -> cols c0=head*32+p4*4 .. +3.
// kv gather: one dwordx4/lane = {k[c0..c0+3], v[c0..c0+3]}; head dot = 3 shfl rounds.
// No-max softmax (exp clamp 80); halves combined exactly via shfl_xor(·,32).

__global__ __launch_bounds__(256) void k_conv(const int* __restrict__ rowstart,
                                              const int4* __restrict__ rec,
                                              const u16* __restrict__ qkvs,
                                              const float* __restrict__ We,
                                              u16* __restrict__ out) {
    int n = blockIdx.x * 4 + (threadIdx.x >> 6);
    int l = threadIdx.x & 63;
    int half = l >> 5;
    int li = l & 31;
    int c0 = (li >> 3) * 32 + (li & 7) * 4;
    const u16* qrow = qkvs + (size_t)n * 512;
    uint2 qu = *(const uint2*)(qrow + c0);
    float q0 = blo(qu.x), q1 = bhi(qu.x), q2 = blo(qu.y), q3 = bhi(qu.y);
    float w00 = We[c0 * 3 + 0], w01 = We[c0 * 3 + 1], w02 = We[c0 * 3 + 2];
    float w10 = We[c0 * 3 + 3], w11 = We[c0 * 3 + 4], w12 = We[c0 * 3 + 5];
    float w20 = We[c0 * 3 + 6], w21 = We[c0 * 3 + 7], w22 = We[c0 * 3 + 8];
    float w30 = We[c0 * 3 + 9], w31 = We[c0 * 3 + 10], w32 = We[c0 * 3 + 11];
    // g_j = sum over head cols of q_c * We[c][j] (8-lane reduce within head)
    float g0 = fmaf(q3, w30, fmaf(q2, w20, fmaf(q1, w10, q0 * w00)));
    float g1 = fmaf(q3, w31, fmaf(q2, w21, fmaf(q1, w11, q0 * w01)));
    float g2 = fmaf(q3, w32, fmaf(q2, w22, fmaf(q1, w12, q0 * w02)));
#pragma unroll
    for (int d = 1; d <= 4; d <<= 1) {
        g0 += __shfl_xor(g0, d);
        g1 += __shfl_xor(g1, d);
        g2 += __shfl_xor(g2, d);
    }
    int e0 = rowstart[n], e1 = rowstart[n + 1];
    float ss = 0.f, o0 = 0.f, o1 = 0.f, o2 = 0.f, o3 = 0.f, S0 = 0.f, S1 = 0.f, S2 = 0.f;
    int kvoff = 128 + li * 8;   // (c0>>2)*8 == li*8

    auto edge = [&](int4 r, uint4 kv) {
        float part = fmaf(q3, bhi(kv.y), fmaf(q2, blo(kv.y), fmaf(q1, bhi(kv.x), q0 * blo(kv.x))));
        part += __shfl_xor(part, 1);
        part += __shfl_xor(part, 2);
        part += __shfl_xor(part, 4);
        float ea0 = __int_as_float(r.y), ea1 = __int_as_float(r.z), ea2 = __int_as_float(r.w);
        float alpha = fmaf(ea2, g2, fmaf(ea1, g1, fmaf(ea0, g0, part))) * 0.17677669529663687f;
        float p = __expf(fminf(alpha, 80.f));
        o0 = fmaf(p, blo(kv.z), o0);
        o1 = fmaf(p, bhi(kv.z), o1);
        o2 = fmaf(p, blo(kv.w), o2);
        o3 = fmaf(p, bhi(kv.w), o3);
        ss += p;
        S0 = fmaf(p, ea0, S0);
        S1 = fmaf(p, ea1, S1);
        S2 = fmaf(p, ea2, S2);
    };

    int e = e0 + half;
    int cnt = (e < e1) ? ((e1 - e + 1) >> 1) : 0;
    if (cnt & 1) {
        int4 r = rec[e];
        uint4 kv = *(const uint4*)(qkvs + (size_t)r.x * 512 + kvoff);
        edge(r, kv);
        e += 2;
    }
    for (int i = 0; i < (cnt >> 1); ++i, e += 4) {
        int4 ra = rec[e], rb = rec[e + 2];
        uint4 kva = *(const uint4*)(qkvs + (size_t)ra.x * 512 + kvoff);
        uint4 kvb = *(const uint4*)(qkvs + (size_t)rb.x * 512 + kvoff);
        edge(ra, kva);
        edge(rb, kvb);
    }
    // combine the two half-wave partials (exact additive)
    o0 += __shfl_xor(o0, 32);
    o1 += __shfl_xor(o1, 32);
    o2 += __shfl_xor(o2, 32);
    o3 += __shfl_xor(o3, 32);
    ss += __shfl_xor(ss, 32);
    S0 += __shfl_xor(S0, 32);
    S1 += __shfl_xor(S1, 32);
    S2 += __shfl_xor(S2, 32);
    if (half == 0) {
        float inv = __builtin_amdgcn_rcpf(fmaxf(ss, 1e-16f));
        o0 = fmaf(w02, S2, fmaf(w01, S1, fmaf(w00, S0, o0)));
        o1 = fmaf(w12, S2, fmaf(w11, S1, fmaf(w10, S0, o1)));
        o2 = fmaf(w22, S2, fmaf(w21, S1, fmaf(w20, S0, o2)));
        o3 = fmaf(w32, S2, fmaf(w31, S1, fmaf(w30, S0, o3)));
        uint2 su = *(const uint2*)(qrow + 384 + c0);
        float r0v = fmaf(o0, inv, blo(su.x));
        float r1v = fmaf(o1, inv, bhi(su.x));
        float r2v = fmaf(o2, inv, blo(su.y));
        float r3v = fmaf(o3, inv, bhi(su.y));
        uint2 ou;
        ou.x = (u32)f2us(r0v) | ((u32)f2us(r1v) << 16);
        ou.y = (u32)f2us(r2v) | ((u32)f2us(r3v) << 16);
        *(uint2*)(out + (size_t)n * 128 + c0) = ou;
    }
}

// ---------------- launcher ----------------

extern "C" void kernel_launch(void* const* d_in, const int* in_sizes, int n_in,
                              void* d_out, int out_size, void* d_ws, size_t ws_size,
                              hipStream_t stream) {
    const float* x = (const float*)d_in[0];
    const int* ei = (const int*)d_in[1];
    const float* eattr = (const float*)d_in[2];
    const float* Wq1 = (const float*)d_in[3];
    const float* Wk1 = (const float*)d_in[4];
    const float* Wv1 = (const float*)d_in[5];
    const float* We1 = (const float*)d_in[6];
    const float* Ws1 = (const float*)d_in[7];
    const float* M1a = (const float*)d_in[8];
    const float* b1a = (const float*)d_in[9];
    const float* M1b = (const float*)d_in[10];
    const float* b1b = (const float*)d_in[11];
    const float* Wq2 = (const float*)d_in[12];
    const float* Wk2 = (const float*)d_in[13];
    const float* Wv2 = (const float*)d_in[14];
    const float* We2 = (const float*)d_in[15];
    const float* Ws2 = (const float*)d_in[16];
    const float* M2a = (const float*)d_in[17];
    const float* b2a = (const float*)d_in[18];
    const float* M2b = (const float*)d_in[19];
    const float* b2b = (const float*)d_in[20];
    const float* Wf1 = (const float*)d_in[21];
    const float* bf1 = (const float*)d_in[22];
    const float* Wf2 = (const float*)d_in[23];
    const float* bf2 = (const float*)d_in[24];

    char* ws = (char*)d_ws;
    size_t off = 0;
    auto alloc = [&](size_t bytes) -> void* {
        void* p = ws + off;
        off = (off + bytes + 255) & ~(size_t)255;
        return p;
    };
    int* deg = (int*)alloc((size_t)NN * 4);
    int* rowstart = (int*)alloc((size_t)(NN + 1) * 4);
    int* cursor = (int*)alloc((size_t)NN * 4);
    int* bsum = (int*)alloc((size_t)NB_SCAN * 4);
    int4* rec = (int4*)alloc((size_t)NE * 16);
    u16* QKVS = (u16*)alloc((size_t)NPAD * 512 * 2);
    u16* Ha = (u16*)alloc((size_t)NPAD * 128 * 2);
    // weight order: [Wq1 Wk1 Wv1 Ws1][Wq2 Wk2 Wv2 Ws2][M1a M1b][M2a M2b][Wf1 Wf2]
    u16* WB[14];
    const int wsz[14] = {16384, 16384, 16384, 16384, 16384, 16384, 16384,
                         16384, 16384, 16384, 16384, 16384, 16384, 8192};
    for (int i = 0; i < 14; ++i) WB[i] = (u16*)alloc((size_t)wsz[i] * 2);

    const int* srcv = ei;
    const int* dstv = ei + NE;

    // CSR build
    hipMemsetAsync(deg, 0, (size_t)NN * 4, stream);
    k_hist<<<(NE + 255) / 256, 256, 0, stream>>>(dstv, deg);
    k_scan1<<<NB_SCAN, 256, 0, stream>>>(deg, rowstart, bsum);
    k_scan2<<<1, 256, 0, stream>>>(bsum);
    k_scan3<<<NB_SCAN, 256, 0, stream>>>(bsum, rowstart, cursor);
    k_scatter<<<(NE + 255) / 256, 256, 0, stream>>>(srcv, dstv, eattr, cursor, rec);

    CvtTab tab;
    const float* wsrc[14] = {Wq1, Wk1, Wv1, Ws1, Wq2, Wk2, Wv2, Ws2,
                             M1a, M1b, M2a, M2b, Wf1, Wf2};
    for (int i = 0; i < 14; ++i) { tab.e[i].s = wsrc[i]; tab.e[i].d = WB[i]; tab.e[i].n = wsz[i]; }
    k_cvt_w<<<112, 256, 0, stream>>>(tab);

    dim3 blk(256);
    dim3 grd(NPAD / 64);   // 782
    dim3 gconv(NN / 4);    // 12500

    // layer 1
    k_qkvs1<<<grd, blk, 0, stream>>>(x, WB[0], QKVS);
    k_conv<<<gconv, blk, 0, stream>>>(rowstart, rec, QKVS, We1, Ha);            // H1 = Ha
    // MLP1 + layer-2 QKVS (H2 never hits HBM)
    k_mlp_qkvs<<<grd, blk, 0, stream>>>(Ha, WB[8], b1a, b1b, WB[4], QKVS);
    k_conv<<<gconv, blk, 0, stream>>>(rowstart, rec, QKVS, We2, Ha);            // H3 = Ha
    // MLP2 + final MLP (H4 never hits HBM)
    k_mlp_final<<<grd, blk, 0, stream>>>(Ha, WB[10], b2a, b2b, WB[12], bf1, bf2, (float*)d_out);
}